// Round 4
// baseline (722.642 us; speedup 1.0000x reference)
//
#include <hip/hip_runtime.h>
#include <math.h>

// DeepHeadClassifier — round 5 (2nd resubmit; two container-infra failures).
// Delta vs r5: __launch_bounds__ back to (NT,2) — occupancy is governed by the
// LDS cut (52992 B -> 3 blocks/CU fit), not the min-waves constraint; removes
// the only untested compiler-facing change as a failure suspect.
// r5 content: (1) LDS 54272->52992 (LN stats union s_attn; gate data in s_buf
// row pads). (2) gate co-scheduled with softmax phases. (3) parallel +
// reassociated reductions (LN1 4thr/row, LN2 16thr/row, 4-acc gate/logits).

#define E   256
#define NC  7
#define BM  16      // rows per block
#define TOK 48      // tokens per block
#define NT  256
#define BS  264     // LDS row stride (elements); row = 528 B (16B-aligned for b128)

typedef unsigned short u16;
typedef unsigned int   u32;
typedef __attribute__((ext_vector_type(8))) short  short8;
typedef __attribute__((ext_vector_type(4))) float  f32x4;

// ws layout (bf16 elements)
#define O_IPW 0
#define O_OW  196608
#define O_GW  262144
#define O_W1  264448
#define O_W2  329984
#define CVT_TOTAL 362752

__device__ __forceinline__ float bf2f(u32 u) { return __uint_as_float(u << 16); }
__device__ __forceinline__ u16 f2bf(float f) {
    u32 u = __float_as_uint(f);
    return (u16)((u + 0x7fffu + ((u >> 16) & 1u)) >> 16);
}

__global__ void cvt_weights(const float* __restrict__ ipw, const float* __restrict__ ow,
                            const float* __restrict__ gw,  const float* __restrict__ w1,
                            const float* __restrict__ w2,  u16* __restrict__ ws) {
    int i4 = (blockIdx.x * 256 + threadIdx.x) * 4;
    if (i4 >= CVT_TOTAL) return;
    const float* src; int off;
    if      (i4 < O_OW)  { src = ipw; off = i4; }
    else if (i4 < O_GW)  { src = ow;  off = i4 - O_OW; }
    else if (i4 < O_W1)  { src = gw;  off = i4 - O_GW; }
    else if (i4 < O_W2)  { src = w1;  off = i4 - O_W1; }
    else                 { src = w2;  off = i4 - O_W2; }
    float4 v = *(const float4*)(src + off);
    ushort4 o;
    o.x = f2bf(v.x); o.y = f2bf(v.y); o.z = f2bf(v.z); o.w = f2bf(v.w);
    *(ushort4*)(ws + i4) = o;
}

// Prefetch ALL B-fragments for one GEMM pass into registers.
template<int NTW>
__device__ __forceinline__ void issue_b(const u16* __restrict__ bW, int rowBase, int lane,
                                        short8 (&b)[8][NTW]) {
    const int l16 = lane & 15, quad = lane >> 4;
    #pragma unroll
    for (int ks = 0; ks < 8; ++ks)
        #pragma unroll
        for (int j = 0; j < NTW; ++j)
            b[ks][j] = *(const short8*)(bW + (size_t)(rowBase + j * 16 + l16) * 256 + ks * 32 + quad * 8);
}

template<int MT, int NTW>
__device__ __forceinline__ void consume_gemm(const u16* aLds, int aRow0, int lane,
                                             const short8 (&b)[8][NTW], f32x4 (&acc)[MT][NTW]) {
    const int l16 = lane & 15, quad = lane >> 4;
    #pragma unroll
    for (int m = 0; m < MT; ++m)
        #pragma unroll
        for (int j = 0; j < NTW; ++j) acc[m][j] = (f32x4){0.f, 0.f, 0.f, 0.f};
    #pragma unroll
    for (int ks = 0; ks < 8; ++ks) {
        short8 a[MT];
        #pragma unroll
        for (int m = 0; m < MT; ++m)
            a[m] = *(const short8*)(aLds + (size_t)(aRow0 + m * 16 + l16) * BS + ks * 32 + quad * 8);
        #pragma unroll
        for (int j = 0; j < NTW; ++j)
            #pragma unroll
            for (int m = 0; m < MT; ++m)
                acc[m][j] = __builtin_amdgcn_mfma_f32_16x16x32_bf16(a[m], b[ks][j], acc[m][j], 0, 0, 0);
    }
}

__global__ __launch_bounds__(NT, 2)
void dhc_mfma_kernel(
    const float* __restrict__ f0, const float* __restrict__ f1, const float* __restrict__ f2,
    const float* __restrict__ ipb, const float* __restrict__ ob,
    const float* __restrict__ ln1g, const float* __restrict__ ln1b,
    const float* __restrict__ gb,
    const float* __restrict__ ln2g, const float* __restrict__ ln2b,
    const float* __restrict__ b1, const float* __restrict__ b2,
    const float* __restrict__ w3, const float* __restrict__ b3,
    const u16* __restrict__ ws, float* __restrict__ d_out, int nrows)
{
    __shared__ __align__(16) u16 s_x[TOK * BS];    // stacked bf16, persists
    __shared__ __align__(16) u16 s_buf[TOK * BS];  // qk -> v/ctx -> x_res/x_ln -> fused/h0/h1/h2
    // 2304 B multi-use block: s_attn [16][4][9] (live P2..P4), then LN stats.
    __shared__ __align__(16) float s_small[576];
    #define S_ATTN(r,h,q) s_small[((r) * 4 + (h)) * 9 + (q)]
    float* s_mu    = s_small;        // [48]  live LN1 (after P4)
    float* s_rstd  = s_small + 48;   // [48]
    float* s_mu2   = s_small + 96;   // [16]  live LN2
    float* s_rstd2 = s_small + 112;  // [16]

    const int tid  = threadIdx.x;
    const int wid  = tid >> 6, lane = tid & 63;
    const int l16  = lane & 15, quad = lane >> 4;
    const long long row0 = (long long)blockIdx.x * BM;
    const size_t fused_base = (size_t)nrows * NC;

    // gate partials (144 floats) + gate weights (48 floats) live in the unused
    // row pads of s_buf (cols 256..263 = 16 B/row, untouched by all writers).
    auto pad_slot = [&](int i) -> float* {
        return (float*)(s_buf + (i >> 2) * BS + 256) + (i & 3);
    };
    // i in [0,144): gate partial idx; i in [144,192): gate weight idx (rows 36..47)

    const u16* ipw_b = ws + O_IPW;
    const u16* ow_b  = ws + O_OW;
    const u16* gw_b  = ws + O_GW;
    const u16* w1_b  = ws + O_W1;
    const u16* w2_b  = ws + O_W2;

    short8 bq[8][4];   // prefetched B fragments, reused per pass
    short8 b5[8][2];   // w2 pass

    const int rb0 = (wid < 2) ? (64 * wid) : (256 + 64 * (wid - 2));
    issue_b<4>(ipw_b, rb0, lane, bq);

    // ---- P0: stacked fp32 -> bf16 LDS (token t = s*16+r) ----
    #pragma unroll
    for (int it = 0; it < 12; ++it) {
        int id = it * NT + tid;
        int t  = id >> 6;
        int c4 = (id & 63) * 4;
        int s  = t >> 4, r = t & 15;
        float4 v = {0.f, 0.f, 0.f, 0.f};
        if (row0 + r < nrows) {
            const float* src = (s == 0 ? f0 : (s == 1 ? f1 : f2));
            v = *(const float4*)(src + (size_t)(row0 + r) * E + c4);
        }
        ushort4 o;
        o.x = f2bf(v.x); o.y = f2bf(v.y); o.z = f2bf(v.z); o.w = f2bf(v.w);
        *(ushort4*)(s_x + t * BS + c4) = o;
    }
    __syncthreads();

    // ---- qk passes: p=0 -> heads 0,1 ; p=1 -> heads 2,3 ----
    for (int p = 0; p < 2; ++p) {
        const int rb = rb0 + 128 * p;
        f32x4 acc[3][4];
        consume_gemm<3, 4>(s_x, 0, lane, bq, acc);
        issue_b<4>(ipw_b, (p == 0) ? (rb0 + 128) : (512 + 64 * wid), lane, bq);
        #pragma unroll
        for (int j = 0; j < 4; ++j) {
            int n = wid * 64 + j * 16 + l16;
            float bias = ipb[rb + j * 16 + l16];
            #pragma unroll
            for (int m = 0; m < 3; ++m)
                #pragma unroll
                for (int rr = 0; rr < 4; ++rr) {
                    int tok = m * 16 + quad * 4 + rr;
                    s_buf[tok * BS + n] = f2bf(acc[m][j][rr] + bias);
                }
        }
        __syncthreads();
        // ---- co-phase: softmax (tid<96) || gate partial (p0) / gate finish (p1) ----
        if (tid < 96) {
            int r = tid / 6, rem = tid % 6;
            int hh = rem / 3, i = rem % 3;
            int h = 2 * p + hh;
            float d0a = 0.f, d0b = 0.f, d1a = 0.f, d1b = 0.f, d2a = 0.f, d2b = 0.f;
            const u16* qrow = s_buf + (i * 16 + r) * BS + hh * 64;
            const u16* k0 = s_buf + (0 * 16 + r) * BS + 128 + hh * 64;
            const u16* k1 = s_buf + (1 * 16 + r) * BS + 128 + hh * 64;
            const u16* k2 = s_buf + (2 * 16 + r) * BS + 128 + hh * 64;
            for (int d8 = 0; d8 < 8; ++d8) {
                short8 qv = *(const short8*)(qrow + d8 * 8);
                short8 a0 = *(const short8*)(k0 + d8 * 8);
                short8 a1 = *(const short8*)(k1 + d8 * 8);
                short8 a2 = *(const short8*)(k2 + d8 * 8);
                #pragma unroll
                for (int e = 0; e < 4; ++e) {
                    float qa = bf2f((u32)(u16)qv[e]);
                    float qb = bf2f((u32)(u16)qv[e + 4]);
                    d0a += qa * bf2f((u32)(u16)a0[e]); d0b += qb * bf2f((u32)(u16)a0[e + 4]);
                    d1a += qa * bf2f((u32)(u16)a1[e]); d1b += qb * bf2f((u32)(u16)a1[e + 4]);
                    d2a += qa * bf2f((u32)(u16)a2[e]); d2b += qb * bf2f((u32)(u16)a2[e + 4]);
                }
            }
            float d0 = (d0a + d0b) * 0.125f, d1 = (d1a + d1b) * 0.125f, d2 = (d2a + d2b) * 0.125f;
            float mx = fmaxf(d0, fmaxf(d1, d2));
            float e0 = __expf(d0 - mx), e1 = __expf(d1 - mx), e2 = __expf(d2 - mx);
            float inv = 1.f / (e0 + e1 + e2);
            S_ATTN(r, h, i * 3 + 0) = e0 * inv;
            S_ATTN(r, h, i * 3 + 1) = e1 * inv;
            S_ATTN(r, h, i * 3 + 2) = e2 * inv;
        } else if (p == 0 && tid < 240) {
            // gate partial: idx -> (r, g, s); reads stable s_x + gw (L2-hot)
            int idx = tid - 96;
            int r = idx / 9, rem = idx % 9;
            int g = rem / 3, s = rem % 3;
            const u16* xp = s_x + (s * 16 + r) * BS;
            const u16* wp = gw_b + g * 768 + s * 256;
            float a0 = 0.f, a1 = 0.f, a2 = 0.f, a3 = 0.f;
            for (int c8 = 0; c8 < 8; ++c8) {
                #pragma unroll
                for (int q4 = 0; q4 < 4; ++q4) {
                    short8 xv = *(const short8*)(xp + (c8 * 4 + q4) * 8);
                    short8 wv = *(const short8*)(wp + (c8 * 4 + q4) * 8);
                    float t = 0.f;
                    #pragma unroll
                    for (int e = 0; e < 8; ++e)
                        t += bf2f((u32)(u16)xv[e]) * bf2f((u32)(u16)wv[e]);
                    if      (q4 == 0) a0 += t;
                    else if (q4 == 1) a1 += t;
                    else if (q4 == 2) a2 += t;
                    else              a3 += t;
                }
            }
            *pad_slot(idx) = (a0 + a1) + (a2 + a3);
        } else if (p == 1 && tid < 112) {
            // gate finish: sum partials + softmax -> wgt pads
            int r = tid - 96;
            float l[3];
            #pragma unroll
            for (int g = 0; g < 3; ++g)
                l[g] = gb[g] + *pad_slot(r * 9 + g * 3 + 0)
                             + *pad_slot(r * 9 + g * 3 + 1)
                             + *pad_slot(r * 9 + g * 3 + 2);
            float mx = fmaxf(l[0], fmaxf(l[1], l[2]));
            float e0 = __expf(l[0] - mx), e1 = __expf(l[1] - mx), e2 = __expf(l[2] - mx);
            float inv = 1.f / (e0 + e1 + e2);
            *pad_slot(144 + r * 3 + 0) = e0 * inv;
            *pad_slot(144 + r * 3 + 1) = e1 * inv;
            *pad_slot(144 + r * 3 + 2) = e2 * inv;
        }
        __syncthreads();
    }

    // ---- G2: v = x @ ipw[512:768]^T + b -> buf[:, 0:256) ----
    {
        const int rb = 512 + 64 * wid;
        f32x4 acc[3][4];
        consume_gemm<3, 4>(s_x, 0, lane, bq, acc);
        issue_b<4>(ow_b, 64 * wid, lane, bq);
        #pragma unroll
        for (int j = 0; j < 4; ++j) {
            int n = wid * 64 + j * 16 + l16;
            float bias = ipb[rb + j * 16 + l16];
            #pragma unroll
            for (int m = 0; m < 3; ++m)
                #pragma unroll
                for (int rr = 0; rr < 4; ++rr) {
                    int tok = m * 16 + quad * 4 + rr;
                    s_buf[tok * BS + n] = f2bf(acc[m][j][rr] + bias);
                }
        }
    }
    __syncthreads();

    // ---- P4: ctx = attn (x) v, in place ----
    {
        int r = tid >> 4;
        int cb = (tid & 15) * 16;
        int h = cb >> 6;
        float a[9];
        #pragma unroll
        for (int q2 = 0; q2 < 9; ++q2) a[q2] = S_ATTN(r, h, q2);
        #pragma unroll
        for (int cc = 0; cc < 16; ++cc) {
            int c = cb + cc;
            float v0 = bf2f((u32)s_buf[(0 * 16 + r) * BS + c]);
            float v1 = bf2f((u32)s_buf[(1 * 16 + r) * BS + c]);
            float v2 = bf2f((u32)s_buf[(2 * 16 + r) * BS + c]);
            float c0 = a[0] * v0 + a[1] * v1 + a[2] * v2;
            float c1 = a[3] * v0 + a[4] * v1 + a[5] * v2;
            float c2 = a[6] * v0 + a[7] * v1 + a[8] * v2;
            s_buf[(0 * 16 + r) * BS + c] = f2bf(c0);
            s_buf[(1 * 16 + r) * BS + c] = f2bf(c1);
            s_buf[(2 * 16 + r) * BS + c] = f2bf(c2);
        }
    }
    __syncthreads();

    // ---- G3: att_out = ctx @ ow^T + ob; + residual -> x_res bf16 in buf ----
    {
        const int rb = 64 * wid;
        f32x4 acc[3][4];
        consume_gemm<3, 4>(s_buf, 0, lane, bq, acc);
        issue_b<4>(w1_b, 64 * wid, lane, bq);
        #pragma unroll
        for (int j = 0; j < 4; ++j) {
            int n = rb + j * 16 + l16;
            float bias = ob[n];
            #pragma unroll
            for (int m = 0; m < 3; ++m)
                #pragma unroll
                for (int rr = 0; rr < 4; ++rr) {
                    int tok = m * 16 + quad * 4 + rr;
                    acc[m][j][rr] += bias + bf2f((u32)s_x[tok * BS + n]);
                }
        }
        __syncthreads();   // all waves done reading ctx
        #pragma unroll
        for (int j = 0; j < 4; ++j) {
            int n = rb + j * 16 + l16;
            #pragma unroll
            for (int m = 0; m < 3; ++m)
                #pragma unroll
                for (int rr = 0; rr < 4; ++rr) {
                    int tok = m * 16 + quad * 4 + rr;
                    s_buf[tok * BS + n] = f2bf(acc[m][j][rr]);
                }
        }
    }
    __syncthreads();

    // ---- LN1 stats: 4 threads/row, shuffle-reduced ----
    if (tid < 192) {
        int r = tid >> 2, j = tid & 3;
        const u16* xp = s_buf + r * BS + j * 64;
        float s0 = 0.f, s1 = 0.f, q0 = 0.f, q1 = 0.f;
        #pragma unroll
        for (int c8 = 0; c8 < 8; ++c8) {
            short8 v = *(const short8*)(xp + c8 * 8);
            #pragma unroll
            for (int e = 0; e < 4; ++e) {
                float xa = bf2f((u32)(u16)v[e]);
                float xb = bf2f((u32)(u16)v[e + 4]);
                s0 += xa; q0 += xa * xa;
                s1 += xb; q1 += xb * xb;
            }
        }
        float sum = s0 + s1, sq = q0 + q1;
        sum += __shfl_xor(sum, 1); sq += __shfl_xor(sq, 1);
        sum += __shfl_xor(sum, 2); sq += __shfl_xor(sq, 2);
        if (j == 0) {
            float mu = sum * (1.f / 256.f);
            float var = sq * (1.f / 256.f) - mu * mu;
            s_mu[r] = mu;
            s_rstd[r] = rsqrtf(var + 1e-5f);
        }
    }
    __syncthreads();
    // ---- LN1 apply in place (thread = column) ----
    {
        float g = ln1g[tid], b = ln1b[tid];
        #pragma unroll 4
        for (int t = 0; t < TOK; ++t) {
            float x = bf2f((u32)s_buf[t * BS + tid]);
            s_buf[t * BS + tid] = f2bf((x - s_mu[t]) * s_rstd[t] * g + b);
        }
    }
    __syncthreads();

    // ---- fused = sum_s wgt*x_ln -> global fp32 + buf rows[0:16) bf16 ----
    {
        int c = tid;
        float* outF = d_out + fused_base;
        #pragma unroll 4
        for (int r = 0; r < BM; ++r) {
            float w0 = *pad_slot(144 + r * 3 + 0);
            float w1v = *pad_slot(144 + r * 3 + 1);
            float w2v = *pad_slot(144 + r * 3 + 2);
            float f = w0  * bf2f((u32)s_buf[(0 * 16 + r) * BS + c])
                    + w1v * bf2f((u32)s_buf[(1 * 16 + r) * BS + c])
                    + w2v * bf2f((u32)s_buf[(2 * 16 + r) * BS + c]);
            if (row0 + r < nrows) outF[(size_t)(row0 + r) * E + c] = f;
            s_buf[r * BS + c] = f2bf(f);
        }
    }
    __syncthreads();

    // ---- LN2 stats: 16 threads/row, shuffle-reduced ----
    {
        int r = tid >> 4, j = tid & 15;
        const u16* fp = s_buf + r * BS + j * 16;
        float sum = 0.f, sq = 0.f;
        #pragma unroll
        for (int c8 = 0; c8 < 2; ++c8) {
            short8 v = *(const short8*)(fp + c8 * 8);
            #pragma unroll
            for (int e = 0; e < 8; ++e) {
                float x = bf2f((u32)(u16)v[e]);
                sum += x; sq += x * x;
            }
        }
        sum += __shfl_xor(sum, 1); sq += __shfl_xor(sq, 1);
        sum += __shfl_xor(sum, 2); sq += __shfl_xor(sq, 2);
        sum += __shfl_xor(sum, 4); sq += __shfl_xor(sq, 4);
        sum += __shfl_xor(sum, 8); sq += __shfl_xor(sq, 8);
        if (j == 0) {
            float mu = sum * (1.f / 256.f);
            float var = sq * (1.f / 256.f) - mu * mu;
            s_mu2[r] = mu;
            s_rstd2[r] = rsqrtf(var + 1e-5f);
        }
    }
    __syncthreads();
    {
        float g = ln2g[tid], b = ln2b[tid];
        #pragma unroll
        for (int r = 0; r < BM; ++r) {
            float x = bf2f((u32)s_buf[r * BS + tid]);
            s_buf[r * BS + tid] = f2bf((x - s_mu2[r]) * s_rstd2[r] * g + b);
        }
    }
    __syncthreads();

    // ---- G4: h1 = gelu(h0 @ w1^T + b1) -> buf rows [16,32) ----
    {
        const int rb = 64 * wid;
        f32x4 acc[1][4];
        consume_gemm<1, 4>(s_buf, 0, lane, bq, acc);
        issue_b<2>(w2_b, 32 * wid, lane, b5);
        __syncthreads();
        #pragma unroll
        for (int j = 0; j < 4; ++j) {
            int n = rb + j * 16 + l16;
            float bias = b1[n];
            #pragma unroll
            for (int rr = 0; rr < 4; ++rr) {
                int r = quad * 4 + rr;
                float x = acc[0][j][rr] + bias;
                float hgelu = 0.5f * x * (1.f + erff(x * 0.70710678118654752f));
                s_buf[(16 + r) * BS + n] = f2bf(hgelu);
            }
        }
    }
    __syncthreads();

    // ---- G5: h2 = gelu(h1 @ w2^T + b2) -> buf rows [32,48), cols [0,128) ----
    {
        const int rb = 32 * wid;
        f32x4 acc[1][2];
        consume_gemm<1, 2>(s_buf, 16, lane, b5, acc);
        __syncthreads();
        #pragma unroll
        for (int j = 0; j < 2; ++j) {
            int n = rb + j * 16 + l16;
            float bias = b2[n];
            #pragma unroll
            for (int rr = 0; rr < 4; ++rr) {
                int r = quad * 4 + rr;
                float x = acc[0][j][rr] + bias;
                float hgelu = 0.5f * x * (1.f + erff(x * 0.70710678118654752f));
                s_buf[(32 + r) * BS + n] = f2bf(hgelu);
            }
        }
    }
    __syncthreads();

    // ---- logits = h2 @ w3^T + b3 -> global fp32 (4-acc reassociated) ----
    if (tid < BM * NC) {
        int r = tid / NC, n = tid % NC;
        const float* wr = w3 + n * 128;
        const u16* hp = s_buf + (32 + r) * BS;
        float a0 = 0.f, a1 = 0.f, a2 = 0.f, a3 = 0.f;
        #pragma unroll
        for (int q8 = 0; q8 < 8; ++q8) {
            #pragma unroll
            for (int q4 = 0; q4 < 4; ++q4) {
                int k4 = q8 * 4 + q4;
                float4 w = *(const float4*)(wr + k4 * 4);
                float t = bf2f((u32)hp[k4 * 4 + 0]) * w.x
                        + bf2f((u32)hp[k4 * 4 + 1]) * w.y
                        + bf2f((u32)hp[k4 * 4 + 2]) * w.z
                        + bf2f((u32)hp[k4 * 4 + 3]) * w.w;
                if      (q4 == 0) a0 += t;
                else if (q4 == 1) a1 += t;
                else if (q4 == 2) a2 += t;
                else              a3 += t;
            }
        }
        float acc = b3[n] + (a0 + a1) + (a2 + a3);
        if (row0 + r < nrows) d_out[(size_t)(row0 + r) * NC + n] = acc;
    }
}

extern "C" void kernel_launch(void* const* d_in, const int* in_sizes, int n_in,
                              void* d_out, int out_size, void* d_ws, size_t ws_size,
                              hipStream_t stream) {
    (void)n_in; (void)ws_size; (void)out_size;
    const int nrows = in_sizes[0] / E;
    u16* ws = (u16*)d_ws;
    cvt_weights<<<(CVT_TOTAL / 4 + 255) / 256, 256, 0, stream>>>(
        (const float*)d_in[3], (const float*)d_in[5], (const float*)d_in[9],
        (const float*)d_in[13], (const float*)d_in[15], ws);
    const int nblocks = (nrows + BM - 1) / BM;
    dhc_mfma_kernel<<<nblocks, NT, 0, stream>>>(
        (const float*)d_in[0], (const float*)d_in[1], (const float*)d_in[2],
        (const float*)d_in[4], (const float*)d_in[6],
        (const float*)d_in[7], (const float*)d_in[8],
        (const float*)d_in[10],
        (const float*)d_in[11], (const float*)d_in[12],
        (const float*)d_in[14], (const float*)d_in[16],
        (const float*)d_in[17], (const float*)d_in[18],
        ws, (float*)d_out, nrows);
}

// Round 5
// 716.506 us; speedup vs baseline: 1.0086x; 1.0086x over previous
//
#include <hip/hip_runtime.h>
#include <math.h>

// DeepHeadClassifier — round 6: decisive LDS cut for occupancy (53KB -> 40KB).
// r5 post-mortem: LDS 53248 already fit 3 blocks arithmetically yet occupancy
// stayed at 2 -> hidden reserve / tighter usable-LDS limit. Kernel is latency-
// bound (stall ~90%, all pipes <25%); the lever is resident blocks. This round
// halves the scratch buffer via N-split attention: s_buf = [48x136] (12.75KB).
// qk -> 4 per-head passes (softmax rides in next pass's phase); v/ctx/out_proj
// -> two half-N passes with G3 K-accumulated in registers; x_res written in
// place into s_x. B-prefetch removed (proven neutral in r4). LDS total 40960 B
// -> 3 blocks/CU fit even under a 128KB-usable hypothesis; 4 under 160KB.

#define E   256
#define NC  7
#define BM  16      // batch rows per block
#define TOK 48      // tokens per block (3 sources x 16 rows)
#define NT  256
#define BSX 264     // s_x stride (elems); 528 B row, 16B-aligned, bank-shift 4
#define BSB 136     // s_buf stride during attention (128 data + 8 pad)

typedef unsigned short u16;
typedef unsigned int   u32;
typedef __attribute__((ext_vector_type(8))) short  short8;
typedef __attribute__((ext_vector_type(4))) float  f32x4;

// ws layout (bf16 elements)
#define O_IPW 0
#define O_OW  196608
#define O_GW  262144
#define O_W1  264448
#define O_W2  329984
#define CVT_TOTAL 362752

__device__ __forceinline__ float bf2f(u32 u) { return __uint_as_float(u << 16); }
__device__ __forceinline__ u16 f2bf(float f) {
    u32 u = __float_as_uint(f);
    return (u16)((u + 0x7fffu + ((u >> 16) & 1u)) >> 16);
}

__global__ void cvt_weights(const float* __restrict__ ipw, const float* __restrict__ ow,
                            const float* __restrict__ gw,  const float* __restrict__ w1,
                            const float* __restrict__ w2,  u16* __restrict__ ws) {
    int i4 = (blockIdx.x * 256 + threadIdx.x) * 4;
    if (i4 >= CVT_TOTAL) return;
    const float* src; int off;
    if      (i4 < O_OW)  { src = ipw; off = i4; }
    else if (i4 < O_GW)  { src = ow;  off = i4 - O_OW; }
    else if (i4 < O_W1)  { src = gw;  off = i4 - O_GW; }
    else if (i4 < O_W2)  { src = w1;  off = i4 - O_W1; }
    else                 { src = w2;  off = i4 - O_W2; }
    float4 v = *(const float4*)(src + off);
    ushort4 o;
    o.x = f2bf(v.x); o.y = f2bf(v.y); o.z = f2bf(v.z); o.w = f2bf(v.w);
    *(ushort4*)(ws + i4) = o;
}

// Generic MFMA tile GEMM: A from LDS (stride AS, col offset aCol0), B rows from
// global ws ([N][256] bf16), K = KSN*32 starting at bCol0. ZERO: init acc.
template<int MT, int NTW, int KSN, int AS, bool ZERO>
__device__ __forceinline__ void gemm_tile(const u16* aLds, int aRow0, int aCol0,
                                          const u16* __restrict__ bW, int rowBase, int bCol0,
                                          int lane, f32x4 (&acc)[MT][NTW]) {
    const int l16 = lane & 15, quad = lane >> 4;
    if (ZERO) {
        #pragma unroll
        for (int m = 0; m < MT; ++m)
            #pragma unroll
            for (int j = 0; j < NTW; ++j) acc[m][j] = (f32x4){0.f, 0.f, 0.f, 0.f};
    }
    #pragma unroll
    for (int ks = 0; ks < KSN; ++ks) {
        short8 a[MT];
        #pragma unroll
        for (int m = 0; m < MT; ++m)
            a[m] = *(const short8*)(aLds + (size_t)(aRow0 + m * 16 + l16) * AS + aCol0 + ks * 32 + quad * 8);
        #pragma unroll
        for (int j = 0; j < NTW; ++j) {
            short8 b = *(const short8*)(bW + (size_t)(rowBase + j * 16 + l16) * 256 + bCol0 + ks * 32 + quad * 8);
            #pragma unroll
            for (int m = 0; m < MT; ++m)
                acc[m][j] = __builtin_amdgcn_mfma_f32_16x16x32_bf16(a[m], b, acc[m][j], 0, 0, 0);
        }
    }
}

__global__ __launch_bounds__(NT, 2)
void dhc_mfma_kernel(
    const float* __restrict__ f0, const float* __restrict__ f1, const float* __restrict__ f2,
    const float* __restrict__ ipb, const float* __restrict__ ob,
    const float* __restrict__ ln1g, const float* __restrict__ ln1b,
    const float* __restrict__ gb,
    const float* __restrict__ ln2g, const float* __restrict__ ln2b,
    const float* __restrict__ b1, const float* __restrict__ b2,
    const float* __restrict__ w3, const float* __restrict__ b3,
    const u16* __restrict__ ws, float* __restrict__ d_out, int nrows)
{
    __shared__ __align__(16) u16 s_x[TOK * BSX];    // 25344 B: x -> x_res -> x_ln
    __shared__ __align__(16) u16 s_buf[TOK * BSB];  // 13056 B: qk_h -> v/ctx halves -> h0/h1/h2
    __shared__ __align__(16) float s_small[640];    // 2560 B
    // s_small: [0..575] attn[r][h][iq] (dead after P4b; then mu[48]@0, rstd[48]@48,
    //          mu2[16]@96, rstd2[16]@112); [576..623] gate wgt[r][g]
    #define S_ATTN(r,h,q) s_small[((r) * 4 + (h)) * 9 + (q)]

    const int tid  = threadIdx.x;
    const int wid  = tid >> 6, lane = tid & 63;
    const int l16  = lane & 15, quad = lane >> 4;
    const long long row0 = (long long)blockIdx.x * BM;
    const size_t fused_base = (size_t)nrows * NC;

    // gate partials (144 floats) in s_x row pads (cols 256..263, never written
    // by P0/epilogues/LN which all stay in cols 0..255)
    auto gp_slot = [&](int i) -> float* {
        return (float*)(s_x + (i >> 2) * BSX + 256) + (i & 3);
    };

    const u16* ipw_b = ws + O_IPW;
    const u16* ow_b  = ws + O_OW;
    const u16* gw_b  = ws + O_GW;
    const u16* w1_b  = ws + O_W1;
    const u16* w2_b  = ws + O_W2;

    // ---- P0: stacked fp32 -> bf16 LDS (token t = s*16+r) ----
    #pragma unroll
    for (int it = 0; it < 12; ++it) {
        int id = it * NT + tid;            // vec4 chunks over 48*256/4 = 3072
        int t  = id >> 6;
        int c4 = (id & 63) * 4;
        int s  = t >> 4, r = t & 15;
        float4 v = {0.f, 0.f, 0.f, 0.f};
        if (row0 + r < nrows) {
            const float* src = (s == 0 ? f0 : (s == 1 ? f1 : f2));
            v = *(const float4*)(src + (size_t)(row0 + r) * E + c4);
        }
        ushort4 o;
        o.x = f2bf(v.x); o.y = f2bf(v.y); o.z = f2bf(v.z); o.w = f2bf(v.w);
        *(ushort4*)(s_x + t * BSX + c4) = o;
    }
    __syncthreads();

    // lambda: softmax for head hh from s_buf [48][BSB] (cols 0..63 q, 64..127 k)
    auto softmax_head = [&](int hh) {
        int i = tid >> 4, r = tid & 15;     // tid < 48: i in 0..2, r in 0..15
        const u16* qrow = s_buf + (i * 16 + r) * BSB;
        const u16* k0 = s_buf + (0 * 16 + r) * BSB + 64;
        const u16* k1 = s_buf + (1 * 16 + r) * BSB + 64;
        const u16* k2 = s_buf + (2 * 16 + r) * BSB + 64;
        float d0a = 0.f, d0b = 0.f, d1a = 0.f, d1b = 0.f, d2a = 0.f, d2b = 0.f;
        #pragma unroll
        for (int d8 = 0; d8 < 8; ++d8) {
            short8 qv = *(const short8*)(qrow + d8 * 8);
            short8 a0 = *(const short8*)(k0 + d8 * 8);
            short8 a1 = *(const short8*)(k1 + d8 * 8);
            short8 a2 = *(const short8*)(k2 + d8 * 8);
            #pragma unroll
            for (int e = 0; e < 4; ++e) {
                float qa = bf2f((u32)(u16)qv[e]);
                float qb = bf2f((u32)(u16)qv[e + 4]);
                d0a += qa * bf2f((u32)(u16)a0[e]); d0b += qb * bf2f((u32)(u16)a0[e + 4]);
                d1a += qa * bf2f((u32)(u16)a1[e]); d1b += qb * bf2f((u32)(u16)a1[e + 4]);
                d2a += qa * bf2f((u32)(u16)a2[e]); d2b += qb * bf2f((u32)(u16)a2[e + 4]);
            }
        }
        float d0 = (d0a + d0b) * 0.125f, d1 = (d1a + d1b) * 0.125f, d2 = (d2a + d2b) * 0.125f;
        float mx = fmaxf(d0, fmaxf(d1, d2));
        float e0 = __expf(d0 - mx), e1 = __expf(d1 - mx), e2 = __expf(d2 - mx);
        float inv = 1.f / (e0 + e1 + e2);
        S_ATTN(r, hh, i * 3 + 0) = e0 * inv;
        S_ATTN(r, hh, i * 3 + 1) = e1 * inv;
        S_ATTN(r, hh, i * 3 + 2) = e2 * inv;
    };

    // ---- qk: 4 per-head passes. Pass h: q_h -> cols 0..63, k_h -> 64..127.
    // softmax of head h-1 rides inside pass h's consume phase (reads old s_buf).
    for (int h = 0; h < 4; ++h) {
        const int rbh = (wid < 2) ? (64 * h + 32 * wid)
                                  : (256 + 64 * h + 32 * (wid - 2));
        f32x4 acc[3][2];
        gemm_tile<3, 2, 8, BSX, true>(s_x, 0, 0, ipw_b, rbh, 0, lane, acc);
        if (h > 0 && tid < 48) softmax_head(h - 1);
        if (h == 0 && tid >= 48 && tid < 192) {
            // gate partial: idx -> (r, g, s); reads stable s_x + gw (L2-hot)
            int idx = tid - 48;
            int r = idx / 9, rem = idx % 9;
            int g = rem / 3, s = rem % 3;
            const u16* xp = s_x + (s * 16 + r) * BSX;
            const u16* wp = gw_b + g * 768 + s * 256;
            float a0 = 0.f, a1 = 0.f, a2 = 0.f, a3 = 0.f;
            for (int c8 = 0; c8 < 8; ++c8) {
                #pragma unroll
                for (int q4 = 0; q4 < 4; ++q4) {
                    short8 xv = *(const short8*)(xp + (c8 * 4 + q4) * 8);
                    short8 wv = *(const short8*)(wp + (c8 * 4 + q4) * 8);
                    float t = 0.f;
                    #pragma unroll
                    for (int e = 0; e < 8; ++e)
                        t += bf2f((u32)(u16)xv[e]) * bf2f((u32)(u16)wv[e]);
                    if      (q4 == 0) a0 += t;
                    else if (q4 == 1) a1 += t;
                    else if (q4 == 2) a2 += t;
                    else              a3 += t;
                }
            }
            *gp_slot(idx) = (a0 + a1) + (a2 + a3);
        }
        if (h == 1 && tid >= 48 && tid < 64) {
            // gate finish: 16 threads, one row each
            int r = tid - 48;
            float l[3];
            #pragma unroll
            for (int g = 0; g < 3; ++g)
                l[g] = gb[g] + *gp_slot(r * 9 + g * 3 + 0)
                             + *gp_slot(r * 9 + g * 3 + 1)
                             + *gp_slot(r * 9 + g * 3 + 2);
            float mx = fmaxf(l[0], fmaxf(l[1], l[2]));
            float e0 = __expf(l[0] - mx), e1 = __expf(l[1] - mx), e2 = __expf(l[2] - mx);
            float inv = 1.f / (e0 + e1 + e2);
            s_small[576 + r * 3 + 0] = e0 * inv;
            s_small[576 + r * 3 + 1] = e1 * inv;
            s_small[576 + r * 3 + 2] = e2 * inv;
        }
        __syncthreads();
        // epilogue: write q|k half-tile
        const int nl = (wid < 2) ? (32 * wid) : (64 + 32 * (wid - 2));
        #pragma unroll
        for (int j = 0; j < 2; ++j) {
            int nn = nl + j * 16 + l16;
            float bias = ipb[rbh + j * 16 + l16];
            #pragma unroll
            for (int m = 0; m < 3; ++m)
                #pragma unroll
                for (int rr = 0; rr < 4; ++rr) {
                    int tok = m * 16 + quad * 4 + rr;
                    s_buf[tok * BSB + nn] = f2bf(acc[m][j][rr] + bias);
                }
        }
        __syncthreads();
    }

    f32x4 acc3[3][4];   // out_proj accumulator, lives across both halves

    // ---- halves: hv=0 -> v cols 0..127 (heads 0,1); hv=1 -> 128..255 (2,3) ----
    for (int hv = 0; hv < 2; ++hv) {
        // G2 half: v = x @ ipw[512+128hv ...]^T
        {
            const int rb = 512 + 128 * hv + 32 * wid;
            f32x4 acc[3][2];
            gemm_tile<3, 2, 8, BSX, true>(s_x, 0, 0, ipw_b, rb, 0, lane, acc);
            if (hv == 0 && tid < 48) softmax_head(3);   // last head's softmax rides here
            __syncthreads();   // hv=0: softmax_3 reads old s_buf; hv=1: G3a readers drain
            #pragma unroll
            for (int j = 0; j < 2; ++j) {
                int nn = 32 * wid + j * 16 + l16;        // local v-col 0..127
                float bias = ipb[rb + j * 16 + l16];
                #pragma unroll
                for (int m = 0; m < 3; ++m)
                    #pragma unroll
                    for (int rr = 0; rr < 4; ++rr) {
                        int tok = m * 16 + quad * 4 + rr;
                        s_buf[tok * BSB + nn] = f2bf(acc[m][j][rr] + bias);
                    }
            }
        }
        __syncthreads();
        // P4 half: ctx = attn (x) v in place
        {
            int r  = tid >> 4;              // 0..15
            int cb = (tid & 15) * 8;        // 0..120
            int h  = 2 * hv + (cb >> 6);
            float a[9];
            #pragma unroll
            for (int q2 = 0; q2 < 9; ++q2) a[q2] = S_ATTN(r, h, q2);
            #pragma unroll
            for (int cc = 0; cc < 8; ++cc) {
                int c = cb + cc;
                float v0 = bf2f((u32)s_buf[(0 * 16 + r) * BSB + c]);
                float v1 = bf2f((u32)s_buf[(1 * 16 + r) * BSB + c]);
                float v2 = bf2f((u32)s_buf[(2 * 16 + r) * BSB + c]);
                float c0 = a[0] * v0 + a[1] * v1 + a[2] * v2;
                float c1 = a[3] * v0 + a[4] * v1 + a[5] * v2;
                float c2 = a[6] * v0 + a[7] * v1 + a[8] * v2;
                s_buf[(0 * 16 + r) * BSB + c] = f2bf(c0);
                s_buf[(1 * 16 + r) * BSB + c] = f2bf(c1);
                s_buf[(2 * 16 + r) * BSB + c] = f2bf(c2);
            }
        }
        __syncthreads();
        // G3 half: att_out partial, K = 128 (k-cols 128*hv ..)
        if (hv == 0) {
            gemm_tile<3, 4, 4, BSB, true >(s_buf, 0, 0, ow_b, 64 * wid, 0,   lane, acc3);
        } else {
            gemm_tile<3, 4, 4, BSB, false>(s_buf, 0, 0, ow_b, 64 * wid, 128, lane, acc3);
            // epilogue: + ob + residual, x_res written in place into s_x
            #pragma unroll
            for (int j = 0; j < 4; ++j) {
                int n = 64 * wid + j * 16 + l16;
                float bias = ob[n];
                #pragma unroll
                for (int m = 0; m < 3; ++m)
                    #pragma unroll
                    for (int rr = 0; rr < 4; ++rr) {
                        int tok = m * 16 + quad * 4 + rr;
                        float v = acc3[m][j][rr] + bias + bf2f((u32)s_x[tok * BSX + n]);
                        s_x[tok * BSX + n] = f2bf(v);
                    }
            }
        }
        __syncthreads();
    }

    // ---- LN1 stats: 4 threads/row, shuffle-reduced (on s_x = x_res) ----
    if (tid < 192) {
        int r = tid >> 2, j = tid & 3;
        const u16* xp = s_x + r * BSX + j * 64;
        float s0 = 0.f, s1 = 0.f, q0 = 0.f, q1 = 0.f;
        #pragma unroll
        for (int c8 = 0; c8 < 8; ++c8) {
            short8 v = *(const short8*)(xp + c8 * 8);
            #pragma unroll
            for (int e = 0; e < 4; ++e) {
                float xa = bf2f((u32)(u16)v[e]);
                float xb = bf2f((u32)(u16)v[e + 4]);
                s0 += xa; q0 += xa * xa;
                s1 += xb; q1 += xb * xb;
            }
        }
        float sum = s0 + s1, sq = q0 + q1;
        sum += __shfl_xor(sum, 1); sq += __shfl_xor(sq, 1);
        sum += __shfl_xor(sum, 2); sq += __shfl_xor(sq, 2);
        if (j == 0) {
            float mu = sum * (1.f / 256.f);
            float var = sq * (1.f / 256.f) - mu * mu;
            s_small[r] = mu;                 // mu[48]
            s_small[48 + r] = rsqrtf(var + 1e-5f);
        }
    }
    __syncthreads();
    // ---- LN1 apply in place on s_x (thread = column) ----
    {
        float g = ln1g[tid], b = ln1b[tid];
        #pragma unroll 4
        for (int t = 0; t < TOK; ++t) {
            float x = bf2f((u32)s_x[t * BSX + tid]);
            s_x[t * BSX + tid] = f2bf((x - s_small[t]) * s_small[48 + t] * g + b);
        }
    }
    __syncthreads();

    // ---- fused = sum_s wgt*x_ln -> global fp32 + h0 into s_buf rows 0..15 (stride BSX) ----
    {
        int c = tid;
        float* outF = d_out + fused_base;
        #pragma unroll 4
        for (int r = 0; r < BM; ++r) {
            float w0 = s_small[576 + r * 3 + 0];
            float w1v = s_small[576 + r * 3 + 1];
            float w2v = s_small[576 + r * 3 + 2];
            float f = w0  * bf2f((u32)s_x[(0 * 16 + r) * BSX + c])
                    + w1v * bf2f((u32)s_x[(1 * 16 + r) * BSX + c])
                    + w2v * bf2f((u32)s_x[(2 * 16 + r) * BSX + c]);
            if (row0 + r < nrows) outF[(size_t)(row0 + r) * E + c] = f;
            s_buf[r * BSX + c] = f2bf(f);
        }
    }
    __syncthreads();

    // ---- LN2 stats: 16 threads/row, shuffle-reduced ----
    {
        int r = tid >> 4, j = tid & 15;
        const u16* fp = s_buf + r * BSX + j * 16;
        float sum = 0.f, sq = 0.f;
        #pragma unroll
        for (int c8 = 0; c8 < 2; ++c8) {
            short8 v = *(const short8*)(fp + c8 * 8);
            #pragma unroll
            for (int e = 0; e < 8; ++e) {
                float x = bf2f((u32)(u16)v[e]);
                sum += x; sq += x * x;
            }
        }
        sum += __shfl_xor(sum, 1); sq += __shfl_xor(sq, 1);
        sum += __shfl_xor(sum, 2); sq += __shfl_xor(sq, 2);
        sum += __shfl_xor(sum, 4); sq += __shfl_xor(sq, 4);
        sum += __shfl_xor(sum, 8); sq += __shfl_xor(sq, 8);
        if (j == 0) {
            float mu = sum * (1.f / 256.f);
            float var = sq * (1.f / 256.f) - mu * mu;
            s_small[96 + r] = mu;
            s_small[112 + r] = rsqrtf(var + 1e-5f);
        }
    }
    __syncthreads();
    {
        float g = ln2g[tid], b = ln2b[tid];
        #pragma unroll
        for (int r = 0; r < BM; ++r) {
            float x = bf2f((u32)s_buf[r * BSX + tid]);
            s_buf[r * BSX + tid] = f2bf((x - s_small[96 + r]) * s_small[112 + r] * g + b);
        }
    }
    __syncthreads();

    // ---- G4: h1 = gelu(h0 @ w1^T + b1), overwrite rows 0..15 (stride BSX) ----
    {
        f32x4 acc[1][4];
        gemm_tile<1, 4, 8, BSX, true>(s_buf, 0, 0, w1_b, 64 * wid, 0, lane, acc);
        __syncthreads();   // all reads of h0 complete before h1 overwrites
        #pragma unroll
        for (int j = 0; j < 4; ++j) {
            int n = 64 * wid + j * 16 + l16;
            float bias = b1[n];
            #pragma unroll
            for (int rr = 0; rr < 4; ++rr) {
                int r = quad * 4 + rr;
                float x = acc[0][j][rr] + bias;
                float hgelu = 0.5f * x * (1.f + erff(x * 0.70710678118654752f));
                s_buf[r * BSX + n] = f2bf(hgelu);
            }
        }
    }
    __syncthreads();

    // ---- G5: h2 = gelu(h1 @ w2^T + b2) -> rows 0..15 at stride BSB ----
    {
        f32x4 acc[1][2];
        gemm_tile<1, 2, 8, BSX, true>(s_buf, 0, 0, w2_b, 32 * wid, 0, lane, acc);
        __syncthreads();   // all reads of h1 complete before h2 (aliasing region)
        #pragma unroll
        for (int j = 0; j < 2; ++j) {
            int n = 32 * wid + j * 16 + l16;      // 0..127
            float bias = b2[n];
            #pragma unroll
            for (int rr = 0; rr < 4; ++rr) {
                int r = quad * 4 + rr;
                float x = acc[0][j][rr] + bias;
                float hgelu = 0.5f * x * (1.f + erff(x * 0.70710678118654752f));
                s_buf[r * BSB + n] = f2bf(hgelu);
            }
        }
    }
    __syncthreads();

    // ---- logits = h2 @ w3^T + b3 -> global fp32 (4-acc) ----
    if (tid < BM * NC) {
        int r = tid / NC, n = tid % NC;
        const float* wr = w3 + n * 128;
        const u16* hp = s_buf + r * BSB;
        float a0 = 0.f, a1 = 0.f, a2 = 0.f, a3 = 0.f;
        #pragma unroll
        for (int q8 = 0; q8 < 8; ++q8) {
            #pragma unroll
            for (int q4 = 0; q4 < 4; ++q4) {
                int k4 = q8 * 4 + q4;
                float4 w = *(const float4*)(wr + k4 * 4);
                float t = bf2f((u32)hp[k4 * 4 + 0]) * w.x
                        + bf2f((u32)hp[k4 * 4 + 1]) * w.y
                        + bf2f((u32)hp[k4 * 4 + 2]) * w.z
                        + bf2f((u32)hp[k4 * 4 + 3]) * w.w;
                if      (q4 == 0) a0 += t;
                else if (q4 == 1) a1 += t;
                else if (q4 == 2) a2 += t;
                else              a3 += t;
            }
        }
        float acc = b3[n] + (a0 + a1) + (a2 + a3);
        if (row0 + r < nrows) d_out[(size_t)(row0 + r) * NC + n] = acc;
    }
}

extern "C" void kernel_launch(void* const* d_in, const int* in_sizes, int n_in,
                              void* d_out, int out_size, void* d_ws, size_t ws_size,
                              hipStream_t stream) {
    (void)n_in; (void)ws_size; (void)out_size;
    const int nrows = in_sizes[0] / E;
    u16* ws = (u16*)d_ws;
    cvt_weights<<<(CVT_TOTAL / 4 + 255) / 256, 256, 0, stream>>>(
        (const float*)d_in[3], (const float*)d_in[5], (const float*)d_in[9],
        (const float*)d_in[13], (const float*)d_in[15], ws);
    const int nblocks = (nrows + BM - 1) / BM;
    dhc_mfma_kernel<<<nblocks, NT, 0, stream>>>(
        (const float*)d_in[0], (const float*)d_in[1], (const float*)d_in[2],
        (const float*)d_in[4], (const float*)d_in[6],
        (const float*)d_in[7], (const float*)d_in[8],
        (const float*)d_in[10],
        (const float*)d_in[11], (const float*)d_in[12],
        (const float*)d_in[14], (const float*)d_in[16],
        (const float*)d_in[17], (const float*)d_in[18],
        ws, (float*)d_out, nrows);
}